// Round 25
// baseline (182.038 us; speedup 1.0000x reference)
//
#include <hip/hip_runtime.h>
#include <hip/hip_bf16.h>
#include <math.h>

#define BB 16
#define LL 200
#define HH 128
#define DD 64
#define NQT 25          // 200/8 q-tiles
#define NEGF -4294967295.0f
#define SQRTH 11.313708498984761f
#define WSTR 129        // LDS row stride for staged weights (conflict-free reads)

// stage a 128x128 row-major weight matrix into w_lds[c*WSTR + k] (1024 threads)
__device__ __forceinline__ void stage_w(const float* __restrict__ W,
                                        float* __restrict__ w_lds, int t) {
#pragma unroll
    for (int i = 0; i < 4; ++i) {
        int x = t + i * 1024;              // 4096 float4 total
        int c = x >> 5, k4 = x & 31;
        float4 v = ((const float4*)W)[x];
        float* dst = w_lds + c * WSTR + k4 * 4;
        dst[0] = v.x; dst[1] = v.y; dst[2] = v.z; dst[3] = v.w;
    }
}

// T14 async-stage split: issue global loads early (prefetch), LDS-write late (commit)
__device__ __forceinline__ void prefetch_w(const float* __restrict__ W,
                                           float4* __restrict__ r, int t) {
#pragma unroll
    for (int i = 0; i < 4; ++i) r[i] = ((const float4*)W)[t + i * 1024];
}
__device__ __forceinline__ void commit_w(const float4* __restrict__ r,
                                         float* __restrict__ w_lds, int t) {
#pragma unroll
    for (int i = 0; i < 4; ++i) {
        int x = t + i * 1024;
        int c = x >> 5, k4 = x & 31;
        float* dst = w_lds + c * WSTR + k4 * 4;
        dst[0] = r[i].x; dst[1] = r[i].y; dst[2] = r[i].z; dst[3] = r[i].w;
    }
}

// 64-lane xor-tree sum
__device__ __forceinline__ float wsum64(float v) {
    v += __shfl_xor(v, 1, 64);  v += __shfl_xor(v, 2, 64);
    v += __shfl_xor(v, 4, 64);  v += __shfl_xor(v, 8, 64);
    v += __shfl_xor(v, 16, 64); v += __shfl_xor(v, 32, 64);
    return v;
}

// ---------------- QKV projection (16 rows/block, 1024 threads), with embed (layer 0).
// Weights LDS-staged with register prefetch (Wq -> Wk -> Wv). ----------------
__global__ __launch_bounds__(1024) void k_qkv(float* __restrict__ seqs,
    const int* __restrict__ log_seqs, const float* __restrict__ item_emb,
    const float* __restrict__ Wq, const float* __restrict__ bq,
    const float* __restrict__ Wk, const float* __restrict__ bk,
    const float* __restrict__ Wv, const float* __restrict__ bv,
    const float* __restrict__ posK, const float* __restrict__ posV,
    float* __restrict__ Q, float* __restrict__ Kp, float* __restrict__ Vp) {
    __shared__ float s_lds[16][HH];
    __shared__ float w_lds[HH * WSTR];
    int r0g = blockIdx.x * 16;
    int t = threadIdx.x;
    if (t < 512) {
        int r = t >> 5, d4 = t & 31;          // 16 rows x 32 float4
        int id = log_seqs[r0g + r];
        float4 v = make_float4(0.f, 0.f, 0.f, 0.f);
        if (id != 0) {
            v = ((const float4*)(item_emb + id * HH))[d4];
            v.x *= SQRTH; v.y *= SQRTH; v.z *= SQRTH; v.w *= SQRTH;
        }
        *(float4*)&s_lds[r][d4 * 4] = v;
        ((float4*)(seqs + r0g * HH))[t] = v;
    }
    stage_w(Wq, w_lds, t);
    __syncthreads();
    int c = t & 127, rg = t >> 7;             // rg 0..7 -> rows rg*2, rg*2+1
    const float* wrow = w_lds + c * WSTR;
    float a0, a1;
    float4 pw[4];
    prefetch_w(Wk, pw, t);                    // hide Wk latency under Q GEMM
    // --- Q ---
    a0 = 0.f; a1 = 0.f;
#pragma unroll 4
    for (int k4 = 0; k4 < 32; ++k4) {
        float w0 = wrow[k4 * 4 + 0], w1 = wrow[k4 * 4 + 1];
        float w2 = wrow[k4 * 4 + 2], w3 = wrow[k4 * 4 + 3];
        float4 s0 = *(const float4*)&s_lds[rg * 2][k4 * 4];
        float4 s1 = *(const float4*)&s_lds[rg * 2 + 1][k4 * 4];
        a0 += s0.x * w0 + s0.y * w1 + s0.z * w2 + s0.w * w3;
        a1 += s1.x * w0 + s1.y * w1 + s1.z * w2 + s1.w * w3;
    }
    Q[(r0g + rg * 2) * HH + c]     = a0 + bq[c];
    Q[(r0g + rg * 2 + 1) * HH + c] = a1 + bq[c];
    __syncthreads();
    commit_w(pw, w_lds, t);
    __syncthreads();
    prefetch_w(Wv, pw, t);                    // hide Wv latency under K GEMM
    // --- K + posK ---
    a0 = 0.f; a1 = 0.f;
#pragma unroll 4
    for (int k4 = 0; k4 < 32; ++k4) {
        float w0 = wrow[k4 * 4 + 0], w1 = wrow[k4 * 4 + 1];
        float w2 = wrow[k4 * 4 + 2], w3 = wrow[k4 * 4 + 3];
        float4 s0 = *(const float4*)&s_lds[rg * 2][k4 * 4];
        float4 s1 = *(const float4*)&s_lds[rg * 2 + 1][k4 * 4];
        a0 += s0.x * w0 + s0.y * w1 + s0.z * w2 + s0.w * w3;
        a1 += s1.x * w0 + s1.y * w1 + s1.z * w2 + s1.w * w3;
    }
    {
        int row0 = r0g + rg * 2, row1 = row0 + 1;
        Kp[row0 * HH + c] = a0 + bk[c] + posK[(row0 % LL) * HH + c];
        Kp[row1 * HH + c] = a1 + bk[c] + posK[(row1 % LL) * HH + c];
    }
    __syncthreads();
    commit_w(pw, w_lds, t);
    __syncthreads();
    // --- V + posV ---
    a0 = 0.f; a1 = 0.f;
#pragma unroll 4
    for (int k4 = 0; k4 < 32; ++k4) {
        float w0 = wrow[k4 * 4 + 0], w1 = wrow[k4 * 4 + 1];
        float w2 = wrow[k4 * 4 + 2], w3 = wrow[k4 * 4 + 3];
        float4 s0 = *(const float4*)&s_lds[rg * 2][k4 * 4];
        float4 s1 = *(const float4*)&s_lds[rg * 2 + 1][k4 * 4];
        a0 += s0.x * w0 + s0.y * w1 + s0.z * w2 + s0.w * w3;
        a1 += s1.x * w0 + s1.y * w1 + s1.z * w2 + s1.w * w3;
    }
    {
        int row0 = r0g + rg * 2, row1 = row0 + 1;
        Vp[row0 * HH + c] = a0 + bv[c] + posV[(row0 % LL) * HH + c];
        Vp[row1 * HH + c] = a1 + bv[c] + posV[(row1 % LL) * HH + c];
    }
}

// ---------------- projK[bh,q,tt] = Q[b,q,h,:] . timeK[tt,h,:] ----------------
// grid = 32 bh * 25 qtiles(8); 256 threads: tq = t>>5, ttl = t&31
__global__ __launch_bounds__(256) void k_proj(const float* __restrict__ Q,
    const float* __restrict__ timeK, float* __restrict__ projK) {
    int bh = blockIdx.x / 25, qt = blockIdx.x % 25;
    int b = bh >> 1, h = bh & 1;
    int qlo = qt * 8;
    __shared__ float Qs[8][68];
    __shared__ float TK[32][68];
    int t = threadIdx.x;
    if (t < 128) {
        int r = t >> 4, d4 = t & 15;
        *(float4*)&Qs[r][d4 * 4] =
            ((const float4*)(Q + (b * LL + qlo + r) * HH + h * DD))[d4];
    }
    int tq = t >> 5, ttl = t & 31;
    for (int ch = 0; ch < 9; ++ch) {
        int base = ch * 32;
        __syncthreads();                 // protect TK (and Qs on ch==0)
        for (int x = t; x < 512; x += 256) {
            int i = x >> 4, d4 = x & 15;
            int tt = base + i;
            if (tt < 257)
                *(float4*)&TK[i][d4 * 4] =
                    ((const float4*)(timeK + tt * HH + h * DD))[d4];
        }
        __syncthreads();
        int tt = base + ttl;
        if (tt < 257) {
            float acc = 0.f;
#pragma unroll
            for (int d4 = 0; d4 < 16; ++d4) {
                float4 qv = *(const float4*)&Qs[tq][d4 * 4];
                float4 kv = *(const float4*)&TK[ttl][d4 * 4];
                acc += qv.x * kv.x + qv.y * kv.y + qv.z * kv.z + qv.w * kv.w;
            }
            projK[(bh * LL + qlo + tq) * 257 + tt] = acc;
        }
    }
}

// ---------------- fused scores + register-softmax + hist + PV ----------------
// grid = 32 bh * 25 qtiles(8); 256 threads: tq/g = t>>5, lane = t&31
__global__ __launch_bounds__(256) void k_attn(
    const float* __restrict__ Q, const float* __restrict__ Kp, const float* __restrict__ Vp,
    const float* __restrict__ projK, const float* __restrict__ timeV,
    const int* __restrict__ tm, const int* __restrict__ log_seqs,
    float* __restrict__ attnout) {
    int bh = blockIdx.x / NQT, qt = blockIdx.x % NQT;
    int b = bh >> 1, h = bh & 1;
    int qlo = qt * 8;
    __shared__ float K_s[32][68];
    __shared__ float smemW[457 * 12];        // WT(i,j) = smemW[i*12+j]; probs 0..199, hist 200..456
    __shared__ int s_allmask;
#define WT(i, j) smemW[(i) * 12 + (j)]
    int t = threadIdx.x;
    int tq = t >> 5, lane = t & 31, g = tq;
    int q = qlo + tq;
    int qhi = qlo + 7;

    if (t == 0) s_allmask = 0;
    for (int x = 200 * 12 + t; x < 457 * 12; x += 256) smemW[x] = 0.f;
    float4 qreg[16];
    {
        const float4* qp = (const float4*)(Q + (b * LL + q) * HH + h * DD);
#pragma unroll
        for (int d4 = 0; d4 < 16; ++d4) qreg[d4] = qp[d4];
    }
    const int* tmrow = tm + (b * LL + q) * LL;
    const float* projrow = projK + (bh * LL + q) * 257;
    const int* lsrow = log_seqs + b * LL;

    // phase 1: scores into registers s[7]
    float s[7];
#pragma unroll
    for (int j = 0; j < 7; ++j) s[j] = NEGF;
    int nkc = (qhi >> 5) + 1;                // block-uniform, <= 7
#pragma unroll
    for (int kc = 0; kc < 7; ++kc) {
        if (kc < nkc) {
            int kbase = kc * 32;
            for (int x = t; x < 512; x += 256) {
                int i = x >> 4, d4 = x & 15;
                int k = kbase + i;
                if (k < LL)
                    *(float4*)&K_s[i][d4 * 4] =
                        ((const float4*)(Kp + (b * LL + k) * HH + h * DD))[d4];
            }
            __syncthreads();
            int k = kbase + lane;
            if (k <= q && lsrow[k] != 0) {
                float acc = 0.f;
#pragma unroll
                for (int d4 = 0; d4 < 16; ++d4) {
                    float4 kv = *(const float4*)&K_s[lane][d4 * 4];
                    acc += qreg[d4].x * kv.x + qreg[d4].y * kv.y +
                           qreg[d4].z * kv.z + qreg[d4].w * kv.w;
                }
                s[kc] = (acc + projrow[tmrow[k]]) * 0.125f;
            }
            __syncthreads();
        }
    }

    // phase 2: softmax fully in registers (32 lanes per q row)
    float mx = s[0];
#pragma unroll
    for (int j = 1; j < 7; ++j) mx = fmaxf(mx, s[j]);
    mx = fmaxf(mx, __shfl_xor(mx, 1, 64));
    mx = fmaxf(mx, __shfl_xor(mx, 2, 64));
    mx = fmaxf(mx, __shfl_xor(mx, 4, 64));
    mx = fmaxf(mx, __shfl_xor(mx, 8, 64));
    mx = fmaxf(mx, __shfl_xor(mx, 16, 64));
    bool allmask = (mx == NEGF);             // exp(0)=1 per k -> uniform 1/200, matches ref
    float sum = 0.f;
#pragma unroll
    for (int j = 0; j < 7; ++j) {
        int k = lane + 32 * j;
        float e = (k < LL) ? __expf(s[j] - mx) : 0.f;
        s[j] = e;
        sum += e;
    }
    sum += __shfl_xor(sum, 1, 64);
    sum += __shfl_xor(sum, 2, 64);
    sum += __shfl_xor(sum, 4, 64);
    sum += __shfl_xor(sum, 8, 64);
    sum += __shfl_xor(sum, 16, 64);
    float inv = 1.0f / sum;
    int klim = allmask ? LL : (q + 1);
    if (allmask && lane == 0) s_allmask = 1;
#pragma unroll
    for (int j = 0; j < 7; ++j) {
        int k = lane + 32 * j;
        if (k < LL) {
            float p = s[j] * inv;
            WT(k, tq) = p;
            if (k < klim && p != 0.f)
                atomicAdd(&WT(200 + tmrow[k], tq), p);
        }
    }
    __syncthreads();

    // phase 3: PV — direct coalesced global reads, broadcast LDS weights.
    // Rows whose 8 weights are all zero are skipped (no global load issued):
    // hist rows are mostly empty for small q-tiles, pad rows are zero in probs.
    int kmax = s_allmask ? LL : (qhi + 1);
    float a00=0.f,a01=0.f,a10=0.f,a11=0.f,a20=0.f,a21=0.f,a30=0.f,a31=0.f;
    float a40=0.f,a41=0.f,a50=0.f,a51=0.f,a60=0.f,a61=0.f,a70=0.f,a71=0.f;
#define PV_STEP(WROW, SRCPTR)                                            \
    {                                                                    \
        const float* wr = &WROW;                                         \
        float4 w0 = *(const float4*)wr;                                  \
        float4 w1 = *(const float4*)(wr + 4);                            \
        bool nz = (w0.x != 0.f) || (w0.y != 0.f) || (w0.z != 0.f) ||     \
                  (w0.w != 0.f) || (w1.x != 0.f) || (w1.y != 0.f) ||     \
                  (w1.z != 0.f) || (w1.w != 0.f);                        \
        if (nz) {                                                        \
            float2 vv = *(const float2*)(SRCPTR);                        \
            a00 += w0.x * vv.x; a01 += w0.x * vv.y;                      \
            a10 += w0.y * vv.x; a11 += w0.y * vv.y;                      \
            a20 += w0.z * vv.x; a21 += w0.z * vv.y;                      \
            a30 += w0.w * vv.x; a31 += w0.w * vv.y;                      \
            a40 += w1.x * vv.x; a41 += w1.x * vv.y;                      \
            a50 += w1.y * vv.x; a51 += w1.y * vv.y;                      \
            a60 += w1.z * vv.x; a61 += w1.z * vv.y;                      \
            a70 += w1.w * vv.x; a71 += w1.w * vv.y;                      \
        }                                                                \
    }
    for (int i = g; i < kmax; i += 8)
        PV_STEP(WT(i, 0), Vp + (b * LL + i) * HH + h * DD + lane * 2);
    for (int i = g; i < 257; i += 8)
        PV_STEP(WT(200 + i, 0), timeV + i * HH + h * DD + lane * 2);
#undef PV_STEP
    __syncthreads();
    float* part = smemW;
    part[g * 512 + 0 * 64 + lane * 2] = a00; part[g * 512 + 0 * 64 + lane * 2 + 1] = a01;
    part[g * 512 + 1 * 64 + lane * 2] = a10; part[g * 512 + 1 * 64 + lane * 2 + 1] = a11;
    part[g * 512 + 2 * 64 + lane * 2] = a20; part[g * 512 + 2 * 64 + lane * 2 + 1] = a21;
    part[g * 512 + 3 * 64 + lane * 2] = a30; part[g * 512 + 3 * 64 + lane * 2 + 1] = a31;
    part[g * 512 + 4 * 64 + lane * 2] = a40; part[g * 512 + 4 * 64 + lane * 2 + 1] = a41;
    part[g * 512 + 5 * 64 + lane * 2] = a50; part[g * 512 + 5 * 64 + lane * 2 + 1] = a51;
    part[g * 512 + 6 * 64 + lane * 2] = a60; part[g * 512 + 6 * 64 + lane * 2 + 1] = a61;
    part[g * 512 + 7 * 64 + lane * 2] = a70; part[g * 512 + 7 * 64 + lane * 2 + 1] = a71;
    __syncthreads();
    {
        float ox = 0.f, oy = 0.f;
#pragma unroll
        for (int gg = 0; gg < 8; ++gg) {
            ox += part[gg * 512 + tq * 64 + lane * 2];
            oy += part[gg * 512 + tq * 64 + lane * 2 + 1];
        }
        *(float2*)(attnout + (b * LL + q) * HH + h * DD + lane * 2) =
            make_float2(ox, oy);
    }
#undef WT
}

// ---------------- fused FFN (16 rows/block, 1024 threads, grid 200)
//    s1=LN1(seqs+AO); x2=s1+FFN(s1); y2=LN2(x2)*keep
//    weights LDS-staged with register prefetch (W1 -> W2 -> [Wq -> Wk -> Wv])
//    do_qkv: also next layer's Q/Kp/Vp from y2; do_final: lnf + logits ----------------
__global__ __launch_bounds__(1024) void k_ffn_full(
    float* __restrict__ seqs, const float* __restrict__ AO,
    const float* __restrict__ g1, const float* __restrict__ be1,
    const float* __restrict__ W1, const float* __restrict__ b1,
    const float* __restrict__ W2, const float* __restrict__ b2,
    const float* __restrict__ g2, const float* __restrict__ be2,
    const int* __restrict__ log_seqs,
    int do_qkv,
    const float* __restrict__ Wq, const float* __restrict__ bq,
    const float* __restrict__ Wk, const float* __restrict__ bk,
    const float* __restrict__ Wv, const float* __restrict__ bv,
    const float* __restrict__ posK, const float* __restrict__ posV,
    float* __restrict__ Q, float* __restrict__ Kp, float* __restrict__ Vp,
    int do_final,
    const float* __restrict__ lnf_g, const float* __restrict__ lnf_b,
    const float* __restrict__ item_emb,
    const int* __restrict__ pos_seqs, const int* __restrict__ neg_seqs,
    float* __restrict__ out) {
    __shared__ float s_lds[16][HH];
    __shared__ float h_lds[16][HH];
    __shared__ float w_lds[HH * WSTR];
    int r0g = blockIdx.x * 16;
    int t = threadIdx.x;
    if (t < 512) {
        float4 a = ((const float4*)(seqs + r0g * HH))[t];
        float4 o = ((const float4*)(AO + r0g * HH))[t];
        a.x += o.x; a.y += o.y; a.z += o.z; a.w += o.w;
        ((float4*)s_lds)[t] = a;
    }
    stage_w(W1, w_lds, t);
    __syncthreads();
    int wv = t >> 6, lane = t & 63;          // 16 waves, wave wv owns row wv
    // LN1 in-place (wave per row)
    {
        float x0 = s_lds[wv][lane], x1 = s_lds[wv][lane + 64];
        float mean = wsum64(x0 + x1) * (1.0f / HH);
        float d0 = x0 - mean, d1 = x1 - mean;
        float var = wsum64(d0 * d0 + d1 * d1) * (1.0f / HH);
        float rstd = rsqrtf(var + 1e-8f);
        s_lds[wv][lane]      = d0 * rstd * g1[lane] + be1[lane];
        s_lds[wv][lane + 64] = d1 * rstd * g1[lane + 64] + be1[lane + 64];
    }
    __syncthreads();
    int c = t & 127, rg = t >> 7;            // rg 0..7 -> rows rg*2, rg*2+1
    const float* wrow = w_lds + c * WSTR;
    float a0, a1;
    float4 pw[4];
    prefetch_w(W2, pw, t);                   // hide W2 latency under GEMM1
    // GEMM1 + relu (W1 from LDS)
    a0 = 0.f; a1 = 0.f;
#pragma unroll 4
    for (int k4 = 0; k4 < 32; ++k4) {
        float w0 = wrow[k4 * 4 + 0], w1 = wrow[k4 * 4 + 1];
        float w2 = wrow[k4 * 4 + 2], w3 = wrow[k4 * 4 + 3];
        float4 s0 = *(const float4*)&s_lds[rg * 2][k4 * 4];
        float4 s1 = *(const float4*)&s_lds[rg * 2 + 1][k4 * 4];
        a0 += s0.x * w0 + s0.y * w1 + s0.z * w2 + s0.w * w3;
        a1 += s1.x * w0 + s1.y * w1 + s1.z * w2 + s1.w * w3;
    }
    h_lds[rg * 2][c]     = fmaxf(a0 + b1[c], 0.f);
    h_lds[rg * 2 + 1][c] = fmaxf(a1 + b1[c], 0.f);
    __syncthreads();
    commit_w(pw, w_lds, t);
    __syncthreads();
    if (do_qkv) prefetch_w(Wq, pw, t);       // hide Wq latency under GEMM2
    // GEMM2 (W2 from LDS)
    a0 = 0.f; a1 = 0.f;
#pragma unroll 4
    for (int k4 = 0; k4 < 32; ++k4) {
        float w0 = wrow[k4 * 4 + 0], w1 = wrow[k4 * 4 + 1];
        float w2 = wrow[k4 * 4 + 2], w3 = wrow[k4 * 4 + 3];
        float4 s0 = *(const float4*)&h_lds[rg * 2][k4 * 4];
        float4 s1 = *(const float4*)&h_lds[rg * 2 + 1][k4 * 4];
        a0 += s0.x * w0 + s0.y * w1 + s0.z * w2 + s0.w * w3;
        a1 += s1.x * w0 + s1.y * w1 + s1.z * w2 + s1.w * w3;
    }
    __syncthreads();                          // h_lds reads done
    h_lds[rg * 2][c]     = s_lds[rg * 2][c] + a0 + b2[c];
    h_lds[rg * 2 + 1][c] = s_lds[rg * 2 + 1][c] + a1 + b2[c];
    __syncthreads();
    // LN2 + keep (wave per row); final layer: lnf + logits
    {
        float x0 = h_lds[wv][lane], x1 = h_lds[wv][lane + 64];
        float mean = wsum64(x0 + x1) * (1.0f / HH);
        float d0 = x0 - mean, d1 = x1 - mean;
        float var = wsum64(d0 * d0 + d1 * d1) * (1.0f / HH);
        float rstd = rsqrtf(var + 1e-8f);
        int row = r0g + wv;
        float keep = (log_seqs[row] != 0) ? 1.0f : 0.0f;
        float y0 = (d0 * rstd * g2[lane] + be2[lane]) * keep;
        float y1 = (d1 * rstd * g2[lane + 64] + be2[lane + 64]) * keep;
        if (do_final) {
            float mean2 = wsum64(y0 + y1) * (1.0f / HH);
            float e0 = y0 - mean2, e1 = y1 - mean2;
            float var2 = wsum64(e0 * e0 + e1 * e1) * (1.0f / HH);
            float rstd2 = rsqrtf(var2 + 1e-8f);
            int pid = pos_seqs[row];
            int nid = neg_seqs[row];
            float lf0 = e0 * rstd2 * lnf_g[lane] + lnf_b[lane];
            float lf1 = e1 * rstd2 * lnf_g[lane + 64] + lnf_b[lane + 64];
            float pp = wsum64(lf0 * item_emb[pid * HH + lane] +
                              lf1 * item_emb[pid * HH + lane + 64]);
            float nn = wsum64(lf0 * item_emb[nid * HH + lane] +
                              lf1 * item_emb[nid * HH + lane + 64]);
            if (lane == 0) {
                out[row] = pp;
                out[BB * LL + row] = nn;
            }
        } else {
            seqs[row * HH + lane]      = y0;
            seqs[row * HH + lane + 64] = y1;
            if (do_qkv) {
                s_lds[wv][lane]      = y0;    // park y2 for QKV (own-row writes)
                s_lds[wv][lane + 64] = y1;
            }
        }
    }
    if (!do_qkv) return;
    __syncthreads();
    commit_w(pw, w_lds, t);                  // Wq into LDS
    __syncthreads();
    prefetch_w(Wk, pw, t);                   // hide Wk latency under Q GEMM
    // --- next-layer Q ---
    a0 = 0.f; a1 = 0.f;
#pragma unroll 4
    for (int k4 = 0; k4 < 32; ++k4) {
        float w0 = wrow[k4 * 4 + 0], w1 = wrow[k4 * 4 + 1];
        float w2 = wrow[k4 * 4 + 2], w3 = wrow[k4 * 4 + 3];
        float4 s0 = *(const float4*)&s_lds[rg * 2][k4 * 4];
        float4 s1 = *(const float4*)&s_lds[rg * 2 + 1][k4 * 4];
        a0 += s0.x * w0 + s0.y * w1 + s0.z * w2 + s0.w * w3;
        a1 += s1.x * w0 + s1.y * w1 + s1.z * w2 + s1.w * w3;
    }
    Q[(r0g + rg * 2) * HH + c]     = a0 + bq[c];
    Q[(r0g + rg * 2 + 1) * HH + c] = a1 + bq[c];
    __syncthreads();
    commit_w(pw, w_lds, t);
    __syncthreads();
    prefetch_w(Wv, pw, t);                   // hide Wv latency under K GEMM
    // --- next-layer K + posK ---
    a0 = 0.f; a1 = 0.f;
#pragma unroll 4
    for (int k4 = 0; k4 < 32; ++k4) {
        float w0 = wrow[k4 * 4 + 0], w1 = wrow[k4 * 4 + 1];
        float w2 = wrow[k4 * 4 + 2], w3 = wrow[k4 * 4 + 3];
        float4 s0 = *(const float4*)&s_lds[rg * 2][k4 * 4];
        float4 s1 = *(const float4*)&s_lds[rg * 2 + 1][k4 * 4];
        a0 += s0.x * w0 + s0.y * w1 + s0.z * w2 + s0.w * w3;
        a1 += s1.x * w0 + s1.y * w1 + s1.z * w2 + s1.w * w3;
    }
    {
        int row0 = r0g + rg * 2, row1 = row0 + 1;
        Kp[row0 * HH + c] = a0 + bk[c] + posK[(row0 % LL) * HH + c];
        Kp[row1 * HH + c] = a1 + bk[c] + posK[(row1 % LL) * HH + c];
    }
    __syncthreads();
    commit_w(pw, w_lds, t);
    __syncthreads();
    // --- next-layer V + posV ---
    a0 = 0.f; a1 = 0.f;
#pragma unroll 4
    for (int k4 = 0; k4 < 32; ++k4) {
        float w0 = wrow[k4 * 4 + 0], w1 = wrow[k4 * 4 + 1];
        float w2 = wrow[k4 * 4 + 2], w3 = wrow[k4 * 4 + 3];
        float4 s0 = *(const float4*)&s_lds[rg * 2][k4 * 4];
        float4 s1 = *(const float4*)&s_lds[rg * 2 + 1][k4 * 4];
        a0 += s0.x * w0 + s0.y * w1 + s0.z * w2 + s0.w * w3;
        a1 += s1.x * w0 + s1.y * w1 + s1.z * w2 + s1.w * w3;
    }
    {
        int row0 = r0g + rg * 2, row1 = row0 + 1;
        Vp[row0 * HH + c] = a0 + bv[c] + posV[(row0 % LL) * HH + c];
        Vp[row1 * HH + c] = a1 + bv[c] + posV[(row1 % LL) * HH + c];
    }
}

extern "C" void kernel_launch(void* const* d_in, const int* in_sizes, int n_in,
                              void* d_out, int out_size, void* d_ws, size_t ws_size,
                              hipStream_t stream) {
    const int* log_seqs = (const int*)d_in[1];
    const int* tm       = (const int*)d_in[2];
    const int* pos_seqs = (const int*)d_in[3];
    const int* neg_seqs = (const int*)d_in[4];
    const float* item_emb = (const float*)d_in[5];
    const float* posK   = (const float*)d_in[6];
    const float* posV   = (const float*)d_in[7];
    const float* timeK  = (const float*)d_in[8];
    const float* timeV  = (const float*)d_in[9];
    const float* Wq = (const float*)d_in[10];
    const float* bq = (const float*)d_in[11];
    const float* Wk = (const float*)d_in[12];
    const float* bk = (const float*)d_in[13];
    const float* Wv = (const float*)d_in[14];
    const float* bv = (const float*)d_in[15];
    const float* ln1_g = (const float*)d_in[16];
    const float* ln1_b = (const float*)d_in[17];
    const float* W1 = (const float*)d_in[18];
    const float* b1 = (const float*)d_in[19];
    const float* W2 = (const float*)d_in[20];
    const float* b2 = (const float*)d_in[21];
    const float* ln2_g = (const float*)d_in[22];
    const float* ln2_b = (const float*)d_in[23];
    const float* lnf_g = (const float*)d_in[24];
    const float* lnf_b = (const float*)d_in[25];

    float* ws    = (float*)d_ws;
    float* seqs  = ws;                   // 409600 floats each
    float* Qb    = seqs + 409600;
    float* Kpb   = Qb + 409600;
    float* Vpb   = Kpb + 409600;
    float* AO    = Vpb + 409600;
    float* projK = AO + 409600;          // 32*200*257 = 1,644,800

    // layer 0
    k_qkv<<<BB * LL / 16, 1024, 0, stream>>>(seqs, log_seqs, item_emb,
        Wq, bq, Wk, bk, Wv, bv, posK, posV, Qb, Kpb, Vpb);
    k_proj<<<32 * NQT, 256, 0, stream>>>(Qb, timeK, projK);
    k_attn<<<32 * NQT, 256, 0, stream>>>(Qb, Kpb, Vpb, projK, timeV,
                                         tm, log_seqs, AO);
    // layer-0 FFN fused with layer-1 QKV
    k_ffn_full<<<BB * LL / 16, 1024, 0, stream>>>(seqs, AO,
        ln1_g, ln1_b, W1, b1, W2, b2, ln2_g, ln2_b, log_seqs,
        1, Wq + HH * HH, bq + HH, Wk + HH * HH, bk + HH, Wv + HH * HH, bv + HH,
        posK, posV, Qb, Kpb, Vpb,
        0, lnf_g, lnf_b, item_emb, pos_seqs, neg_seqs, (float*)d_out);
    // layer 1
    k_proj<<<32 * NQT, 256, 0, stream>>>(Qb, timeK, projK);
    k_attn<<<32 * NQT, 256, 0, stream>>>(Qb, Kpb, Vpb, projK, timeV,
                                         tm, log_seqs, AO);
    k_ffn_full<<<BB * LL / 16, 1024, 0, stream>>>(seqs, AO,
        ln1_g + HH, ln1_b + HH, W1 + HH * HH, b1 + HH, W2 + HH * HH, b2 + HH,
        ln2_g + HH, ln2_b + HH, log_seqs,
        0, nullptr, nullptr, nullptr, nullptr, nullptr, nullptr,
        nullptr, nullptr, nullptr, nullptr, nullptr,
        1, lnf_g, lnf_b, item_emb, pos_seqs, neg_seqs, (float*)d_out);
}

// Round 26
// 158.577 us; speedup vs baseline: 1.1479x; 1.1479x over previous
//
#include <hip/hip_runtime.h>
#include <hip/hip_bf16.h>
#include <math.h>

#define BB 16
#define LL 200
#define HH 128
#define DD 64
#define NQT 25          // 200/8 q-tiles
#define NEGF -4294967295.0f
#define SQRTH 11.313708498984761f
#define WSTR 129        // LDS row stride for staged weights (conflict-free reads)

// stage a 128x128 row-major weight matrix into w_lds[c*WSTR + k] (1024 threads)
__device__ __forceinline__ void stage_w(const float* __restrict__ W,
                                        float* __restrict__ w_lds, int t) {
#pragma unroll
    for (int i = 0; i < 4; ++i) {
        int x = t + i * 1024;              // 4096 float4 total
        int c = x >> 5, k4 = x & 31;
        float4 v = ((const float4*)W)[x];
        float* dst = w_lds + c * WSTR + k4 * 4;
        dst[0] = v.x; dst[1] = v.y; dst[2] = v.z; dst[3] = v.w;
    }
}

// T14 async-stage split: issue global loads early (prefetch), LDS-write late (commit)
__device__ __forceinline__ void prefetch_w(const float* __restrict__ W,
                                           float4* __restrict__ r, int t) {
#pragma unroll
    for (int i = 0; i < 4; ++i) r[i] = ((const float4*)W)[t + i * 1024];
}
__device__ __forceinline__ void commit_w(const float4* __restrict__ r,
                                         float* __restrict__ w_lds, int t) {
#pragma unroll
    for (int i = 0; i < 4; ++i) {
        int x = t + i * 1024;
        int c = x >> 5, k4 = x & 31;
        float* dst = w_lds + c * WSTR + k4 * 4;
        dst[0] = r[i].x; dst[1] = r[i].y; dst[2] = r[i].z; dst[3] = r[i].w;
    }
}

// 64-lane xor-tree sum
__device__ __forceinline__ float wsum64(float v) {
    v += __shfl_xor(v, 1, 64);  v += __shfl_xor(v, 2, 64);
    v += __shfl_xor(v, 4, 64);  v += __shfl_xor(v, 8, 64);
    v += __shfl_xor(v, 16, 64); v += __shfl_xor(v, 32, 64);
    return v;
}

// ---------------- QKV projection (16 rows/block, 1024 threads), with embed (layer 0).
// Weights LDS-staged with register prefetch (Wq -> Wk -> Wv). ----------------
__global__ __launch_bounds__(1024) void k_qkv(float* __restrict__ seqs,
    const int* __restrict__ log_seqs, const float* __restrict__ item_emb,
    const float* __restrict__ Wq, const float* __restrict__ bq,
    const float* __restrict__ Wk, const float* __restrict__ bk,
    const float* __restrict__ Wv, const float* __restrict__ bv,
    const float* __restrict__ posK, const float* __restrict__ posV,
    float* __restrict__ Q, float* __restrict__ Kp, float* __restrict__ Vp) {
    __shared__ float s_lds[16][HH];
    __shared__ float w_lds[HH * WSTR];
    int r0g = blockIdx.x * 16;
    int t = threadIdx.x;
    if (t < 512) {
        int r = t >> 5, d4 = t & 31;          // 16 rows x 32 float4
        int id = log_seqs[r0g + r];
        float4 v = make_float4(0.f, 0.f, 0.f, 0.f);
        if (id != 0) {
            v = ((const float4*)(item_emb + id * HH))[d4];
            v.x *= SQRTH; v.y *= SQRTH; v.z *= SQRTH; v.w *= SQRTH;
        }
        *(float4*)&s_lds[r][d4 * 4] = v;
        ((float4*)(seqs + r0g * HH))[t] = v;
    }
    stage_w(Wq, w_lds, t);
    __syncthreads();
    int c = t & 127, rg = t >> 7;             // rg 0..7 -> rows rg*2, rg*2+1
    const float* wrow = w_lds + c * WSTR;
    float a0, a1;
    float4 pw[4];
    prefetch_w(Wk, pw, t);                    // hide Wk latency under Q GEMM
    // --- Q ---
    a0 = 0.f; a1 = 0.f;
#pragma unroll 4
    for (int k4 = 0; k4 < 32; ++k4) {
        float w0 = wrow[k4 * 4 + 0], w1 = wrow[k4 * 4 + 1];
        float w2 = wrow[k4 * 4 + 2], w3 = wrow[k4 * 4 + 3];
        float4 s0 = *(const float4*)&s_lds[rg * 2][k4 * 4];
        float4 s1 = *(const float4*)&s_lds[rg * 2 + 1][k4 * 4];
        a0 += s0.x * w0 + s0.y * w1 + s0.z * w2 + s0.w * w3;
        a1 += s1.x * w0 + s1.y * w1 + s1.z * w2 + s1.w * w3;
    }
    Q[(r0g + rg * 2) * HH + c]     = a0 + bq[c];
    Q[(r0g + rg * 2 + 1) * HH + c] = a1 + bq[c];
    __syncthreads();
    commit_w(pw, w_lds, t);
    __syncthreads();
    prefetch_w(Wv, pw, t);                    // hide Wv latency under K GEMM
    // --- K + posK ---
    a0 = 0.f; a1 = 0.f;
#pragma unroll 4
    for (int k4 = 0; k4 < 32; ++k4) {
        float w0 = wrow[k4 * 4 + 0], w1 = wrow[k4 * 4 + 1];
        float w2 = wrow[k4 * 4 + 2], w3 = wrow[k4 * 4 + 3];
        float4 s0 = *(const float4*)&s_lds[rg * 2][k4 * 4];
        float4 s1 = *(const float4*)&s_lds[rg * 2 + 1][k4 * 4];
        a0 += s0.x * w0 + s0.y * w1 + s0.z * w2 + s0.w * w3;
        a1 += s1.x * w0 + s1.y * w1 + s1.z * w2 + s1.w * w3;
    }
    {
        int row0 = r0g + rg * 2, row1 = row0 + 1;
        Kp[row0 * HH + c] = a0 + bk[c] + posK[(row0 % LL) * HH + c];
        Kp[row1 * HH + c] = a1 + bk[c] + posK[(row1 % LL) * HH + c];
    }
    __syncthreads();
    commit_w(pw, w_lds, t);
    __syncthreads();
    // --- V + posV ---
    a0 = 0.f; a1 = 0.f;
#pragma unroll 4
    for (int k4 = 0; k4 < 32; ++k4) {
        float w0 = wrow[k4 * 4 + 0], w1 = wrow[k4 * 4 + 1];
        float w2 = wrow[k4 * 4 + 2], w3 = wrow[k4 * 4 + 3];
        float4 s0 = *(const float4*)&s_lds[rg * 2][k4 * 4];
        float4 s1 = *(const float4*)&s_lds[rg * 2 + 1][k4 * 4];
        a0 += s0.x * w0 + s0.y * w1 + s0.z * w2 + s0.w * w3;
        a1 += s1.x * w0 + s1.y * w1 + s1.z * w2 + s1.w * w3;
    }
    {
        int row0 = r0g + rg * 2, row1 = row0 + 1;
        Vp[row0 * HH + c] = a0 + bv[c] + posV[(row0 % LL) * HH + c];
        Vp[row1 * HH + c] = a1 + bv[c] + posV[(row1 % LL) * HH + c];
    }
}

// ---------------- projK[bh,q,tt] = Q[b,q,h,:] . timeK[tt,h,:] ----------------
// grid = 32 bh * 25 qtiles(8); 256 threads: tq = t>>5, ttl = t&31
__global__ __launch_bounds__(256) void k_proj(const float* __restrict__ Q,
    const float* __restrict__ timeK, float* __restrict__ projK) {
    int bh = blockIdx.x / 25, qt = blockIdx.x % 25;
    int b = bh >> 1, h = bh & 1;
    int qlo = qt * 8;
    __shared__ float Qs[8][68];
    __shared__ float TK[32][68];
    int t = threadIdx.x;
    if (t < 128) {
        int r = t >> 4, d4 = t & 15;
        *(float4*)&Qs[r][d4 * 4] =
            ((const float4*)(Q + (b * LL + qlo + r) * HH + h * DD))[d4];
    }
    int tq = t >> 5, ttl = t & 31;
    for (int ch = 0; ch < 9; ++ch) {
        int base = ch * 32;
        __syncthreads();                 // protect TK (and Qs on ch==0)
        for (int x = t; x < 512; x += 256) {
            int i = x >> 4, d4 = x & 15;
            int tt = base + i;
            if (tt < 257)
                *(float4*)&TK[i][d4 * 4] =
                    ((const float4*)(timeK + tt * HH + h * DD))[d4];
        }
        __syncthreads();
        int tt = base + ttl;
        if (tt < 257) {
            float acc = 0.f;
#pragma unroll
            for (int d4 = 0; d4 < 16; ++d4) {
                float4 qv = *(const float4*)&Qs[tq][d4 * 4];
                float4 kv = *(const float4*)&TK[ttl][d4 * 4];
                acc += qv.x * kv.x + qv.y * kv.y + qv.z * kv.z + qv.w * kv.w;
            }
            projK[(bh * LL + qlo + tq) * 257 + tt] = acc;
        }
    }
}

// ---------------- fused scores + register-softmax + hist + PV ----------------
// grid = 32 bh * 25 qtiles(8); 256 threads: tq/g = t>>5, lane = t&31
__global__ __launch_bounds__(256) void k_attn(
    const float* __restrict__ Q, const float* __restrict__ Kp, const float* __restrict__ Vp,
    const float* __restrict__ projK, const float* __restrict__ timeV,
    const int* __restrict__ tm, const int* __restrict__ log_seqs,
    float* __restrict__ attnout) {
    int bh = blockIdx.x / NQT, qt = blockIdx.x % NQT;
    int b = bh >> 1, h = bh & 1;
    int qlo = qt * 8;
    __shared__ float K_s[32][68];
    __shared__ float smemW[457 * 12];        // WT(i,j) = smemW[i*12+j]; probs 0..199, hist 200..456
    __shared__ int s_allmask;
#define WT(i, j) smemW[(i) * 12 + (j)]
    int t = threadIdx.x;
    int tq = t >> 5, lane = t & 31, g = tq;
    int q = qlo + tq;
    int qhi = qlo + 7;

    if (t == 0) s_allmask = 0;
    for (int x = 200 * 12 + t; x < 457 * 12; x += 256) smemW[x] = 0.f;
    float4 qreg[16];
    {
        const float4* qp = (const float4*)(Q + (b * LL + q) * HH + h * DD);
#pragma unroll
        for (int d4 = 0; d4 < 16; ++d4) qreg[d4] = qp[d4];
    }
    const int* tmrow = tm + (b * LL + q) * LL;
    const float* projrow = projK + (bh * LL + q) * 257;
    const int* lsrow = log_seqs + b * LL;

    // phase 1: scores into registers s[7]
    float s[7];
#pragma unroll
    for (int j = 0; j < 7; ++j) s[j] = NEGF;
    int nkc = (qhi >> 5) + 1;                // block-uniform, <= 7
#pragma unroll
    for (int kc = 0; kc < 7; ++kc) {
        if (kc < nkc) {
            int kbase = kc * 32;
            for (int x = t; x < 512; x += 256) {
                int i = x >> 4, d4 = x & 15;
                int k = kbase + i;
                if (k < LL)
                    *(float4*)&K_s[i][d4 * 4] =
                        ((const float4*)(Kp + (b * LL + k) * HH + h * DD))[d4];
            }
            __syncthreads();
            int k = kbase + lane;
            if (k <= q && lsrow[k] != 0) {
                float acc = 0.f;
#pragma unroll
                for (int d4 = 0; d4 < 16; ++d4) {
                    float4 kv = *(const float4*)&K_s[lane][d4 * 4];
                    acc += qreg[d4].x * kv.x + qreg[d4].y * kv.y +
                           qreg[d4].z * kv.z + qreg[d4].w * kv.w;
                }
                s[kc] = (acc + projrow[tmrow[k]]) * 0.125f;
            }
            __syncthreads();
        }
    }

    // phase 2: softmax fully in registers (32 lanes per q row)
    float mx = s[0];
#pragma unroll
    for (int j = 1; j < 7; ++j) mx = fmaxf(mx, s[j]);
    mx = fmaxf(mx, __shfl_xor(mx, 1, 64));
    mx = fmaxf(mx, __shfl_xor(mx, 2, 64));
    mx = fmaxf(mx, __shfl_xor(mx, 4, 64));
    mx = fmaxf(mx, __shfl_xor(mx, 8, 64));
    mx = fmaxf(mx, __shfl_xor(mx, 16, 64));
    bool allmask = (mx == NEGF);             // exp(0)=1 per k -> uniform 1/200, matches ref
    float sum = 0.f;
#pragma unroll
    for (int j = 0; j < 7; ++j) {
        int k = lane + 32 * j;
        float e = (k < LL) ? __expf(s[j] - mx) : 0.f;
        s[j] = e;
        sum += e;
    }
    sum += __shfl_xor(sum, 1, 64);
    sum += __shfl_xor(sum, 2, 64);
    sum += __shfl_xor(sum, 4, 64);
    sum += __shfl_xor(sum, 8, 64);
    sum += __shfl_xor(sum, 16, 64);
    float inv = 1.0f / sum;
    int klim = allmask ? LL : (q + 1);
    if (allmask && lane == 0) s_allmask = 1;
#pragma unroll
    for (int j = 0; j < 7; ++j) {
        int k = lane + 32 * j;
        if (k < LL) {
            float p = s[j] * inv;
            WT(k, tq) = p;
            if (k < klim && p != 0.f)
                atomicAdd(&WT(200 + tmrow[k], tq), p);
        }
    }
    __syncthreads();

    // phase 3: PV — direct coalesced global reads, broadcast LDS weights
    int kmax = s_allmask ? LL : (qhi + 1);
    float a00=0.f,a01=0.f,a10=0.f,a11=0.f,a20=0.f,a21=0.f,a30=0.f,a31=0.f;
    float a40=0.f,a41=0.f,a50=0.f,a51=0.f,a60=0.f,a61=0.f,a70=0.f,a71=0.f;
#define PV_STEP(WROW, SRCPTR)                                            \
    {                                                                    \
        const float* wr = &WROW;                                         \
        float4 w0 = *(const float4*)wr;                                  \
        float4 w1 = *(const float4*)(wr + 4);                            \
        float2 vv = *(const float2*)(SRCPTR);                            \
        a00 += w0.x * vv.x; a01 += w0.x * vv.y;                          \
        a10 += w0.y * vv.x; a11 += w0.y * vv.y;                          \
        a20 += w0.z * vv.x; a21 += w0.z * vv.y;                          \
        a30 += w0.w * vv.x; a31 += w0.w * vv.y;                          \
        a40 += w1.x * vv.x; a41 += w1.x * vv.y;                          \
        a50 += w1.y * vv.x; a51 += w1.y * vv.y;                          \
        a60 += w1.z * vv.x; a61 += w1.z * vv.y;                          \
        a70 += w1.w * vv.x; a71 += w1.w * vv.y;                          \
    }
    for (int i = g; i < kmax; i += 8)
        PV_STEP(WT(i, 0), Vp + (b * LL + i) * HH + h * DD + lane * 2);
    for (int i = g; i < 257; i += 8)
        PV_STEP(WT(200 + i, 0), timeV + i * HH + h * DD + lane * 2);
#undef PV_STEP
    __syncthreads();
    float* part = smemW;
    part[g * 512 + 0 * 64 + lane * 2] = a00; part[g * 512 + 0 * 64 + lane * 2 + 1] = a01;
    part[g * 512 + 1 * 64 + lane * 2] = a10; part[g * 512 + 1 * 64 + lane * 2 + 1] = a11;
    part[g * 512 + 2 * 64 + lane * 2] = a20; part[g * 512 + 2 * 64 + lane * 2 + 1] = a21;
    part[g * 512 + 3 * 64 + lane * 2] = a30; part[g * 512 + 3 * 64 + lane * 2 + 1] = a31;
    part[g * 512 + 4 * 64 + lane * 2] = a40; part[g * 512 + 4 * 64 + lane * 2 + 1] = a41;
    part[g * 512 + 5 * 64 + lane * 2] = a50; part[g * 512 + 5 * 64 + lane * 2 + 1] = a51;
    part[g * 512 + 6 * 64 + lane * 2] = a60; part[g * 512 + 6 * 64 + lane * 2 + 1] = a61;
    part[g * 512 + 7 * 64 + lane * 2] = a70; part[g * 512 + 7 * 64 + lane * 2 + 1] = a71;
    __syncthreads();
    {
        float ox = 0.f, oy = 0.f;
#pragma unroll
        for (int gg = 0; gg < 8; ++gg) {
            ox += part[gg * 512 + tq * 64 + lane * 2];
            oy += part[gg * 512 + tq * 64 + lane * 2 + 1];
        }
        *(float2*)(attnout + (b * LL + q) * HH + h * DD + lane * 2) =
            make_float2(ox, oy);
    }
#undef WT
}

// ---------------- fused FFN (16 rows/block, 1024 threads, grid 200)
//    s1=LN1(seqs+AO); x2=s1+FFN(s1); y2=LN2(x2)*keep
//    weights LDS-staged with register prefetch (W1 -> W2 -> [Wq -> Wk -> Wv])
//    do_qkv: also next layer's Q/Kp/Vp from y2; do_final: lnf + logits ----------------
__global__ __launch_bounds__(1024) void k_ffn_full(
    float* __restrict__ seqs, const float* __restrict__ AO,
    const float* __restrict__ g1, const float* __restrict__ be1,
    const float* __restrict__ W1, const float* __restrict__ b1,
    const float* __restrict__ W2, const float* __restrict__ b2,
    const float* __restrict__ g2, const float* __restrict__ be2,
    const int* __restrict__ log_seqs,
    int do_qkv,
    const float* __restrict__ Wq, const float* __restrict__ bq,
    const float* __restrict__ Wk, const float* __restrict__ bk,
    const float* __restrict__ Wv, const float* __restrict__ bv,
    const float* __restrict__ posK, const float* __restrict__ posV,
    float* __restrict__ Q, float* __restrict__ Kp, float* __restrict__ Vp,
    int do_final,
    const float* __restrict__ lnf_g, const float* __restrict__ lnf_b,
    const float* __restrict__ item_emb,
    const int* __restrict__ pos_seqs, const int* __restrict__ neg_seqs,
    float* __restrict__ out) {
    __shared__ float s_lds[16][HH];
    __shared__ float h_lds[16][HH];
    __shared__ float w_lds[HH * WSTR];
    int r0g = blockIdx.x * 16;
    int t = threadIdx.x;
    if (t < 512) {
        float4 a = ((const float4*)(seqs + r0g * HH))[t];
        float4 o = ((const float4*)(AO + r0g * HH))[t];
        a.x += o.x; a.y += o.y; a.z += o.z; a.w += o.w;
        ((float4*)s_lds)[t] = a;
    }
    stage_w(W1, w_lds, t);
    __syncthreads();
    int wv = t >> 6, lane = t & 63;          // 16 waves, wave wv owns row wv
    // LN1 in-place (wave per row)
    {
        float x0 = s_lds[wv][lane], x1 = s_lds[wv][lane + 64];
        float mean = wsum64(x0 + x1) * (1.0f / HH);
        float d0 = x0 - mean, d1 = x1 - mean;
        float var = wsum64(d0 * d0 + d1 * d1) * (1.0f / HH);
        float rstd = rsqrtf(var + 1e-8f);
        s_lds[wv][lane]      = d0 * rstd * g1[lane] + be1[lane];
        s_lds[wv][lane + 64] = d1 * rstd * g1[lane + 64] + be1[lane + 64];
    }
    __syncthreads();
    int c = t & 127, rg = t >> 7;            // rg 0..7 -> rows rg*2, rg*2+1
    const float* wrow = w_lds + c * WSTR;
    float a0, a1;
    float4 pw[4];
    prefetch_w(W2, pw, t);                   // hide W2 latency under GEMM1
    // GEMM1 + relu (W1 from LDS)
    a0 = 0.f; a1 = 0.f;
#pragma unroll 4
    for (int k4 = 0; k4 < 32; ++k4) {
        float w0 = wrow[k4 * 4 + 0], w1 = wrow[k4 * 4 + 1];
        float w2 = wrow[k4 * 4 + 2], w3 = wrow[k4 * 4 + 3];
        float4 s0 = *(const float4*)&s_lds[rg * 2][k4 * 4];
        float4 s1 = *(const float4*)&s_lds[rg * 2 + 1][k4 * 4];
        a0 += s0.x * w0 + s0.y * w1 + s0.z * w2 + s0.w * w3;
        a1 += s1.x * w0 + s1.y * w1 + s1.z * w2 + s1.w * w3;
    }
    h_lds[rg * 2][c]     = fmaxf(a0 + b1[c], 0.f);
    h_lds[rg * 2 + 1][c] = fmaxf(a1 + b1[c], 0.f);
    __syncthreads();
    commit_w(pw, w_lds, t);
    __syncthreads();
    if (do_qkv) prefetch_w(Wq, pw, t);       // hide Wq latency under GEMM2
    // GEMM2 (W2 from LDS)
    a0 = 0.f; a1 = 0.f;
#pragma unroll 4
    for (int k4 = 0; k4 < 32; ++k4) {
        float w0 = wrow[k4 * 4 + 0], w1 = wrow[k4 * 4 + 1];
        float w2 = wrow[k4 * 4 + 2], w3 = wrow[k4 * 4 + 3];
        float4 s0 = *(const float4*)&h_lds[rg * 2][k4 * 4];
        float4 s1 = *(const float4*)&h_lds[rg * 2 + 1][k4 * 4];
        a0 += s0.x * w0 + s0.y * w1 + s0.z * w2 + s0.w * w3;
        a1 += s1.x * w0 + s1.y * w1 + s1.z * w2 + s1.w * w3;
    }
    __syncthreads();                          // h_lds reads done
    h_lds[rg * 2][c]     = s_lds[rg * 2][c] + a0 + b2[c];
    h_lds[rg * 2 + 1][c] = s_lds[rg * 2 + 1][c] + a1 + b2[c];
    __syncthreads();
    // LN2 + keep (wave per row); final layer: lnf + logits
    {
        float x0 = h_lds[wv][lane], x1 = h_lds[wv][lane + 64];
        float mean = wsum64(x0 + x1) * (1.0f / HH);
        float d0 = x0 - mean, d1 = x1 - mean;
        float var = wsum64(d0 * d0 + d1 * d1) * (1.0f / HH);
        float rstd = rsqrtf(var + 1e-8f);
        int row = r0g + wv;
        float keep = (log_seqs[row] != 0) ? 1.0f : 0.0f;
        float y0 = (d0 * rstd * g2[lane] + be2[lane]) * keep;
        float y1 = (d1 * rstd * g2[lane + 64] + be2[lane + 64]) * keep;
        if (do_final) {
            float mean2 = wsum64(y0 + y1) * (1.0f / HH);
            float e0 = y0 - mean2, e1 = y1 - mean2;
            float var2 = wsum64(e0 * e0 + e1 * e1) * (1.0f / HH);
            float rstd2 = rsqrtf(var2 + 1e-8f);
            int pid = pos_seqs[row];
            int nid = neg_seqs[row];
            float lf0 = e0 * rstd2 * lnf_g[lane] + lnf_b[lane];
            float lf1 = e1 * rstd2 * lnf_g[lane + 64] + lnf_b[lane + 64];
            float pp = wsum64(lf0 * item_emb[pid * HH + lane] +
                              lf1 * item_emb[pid * HH + lane + 64]);
            float nn = wsum64(lf0 * item_emb[nid * HH + lane] +
                              lf1 * item_emb[nid * HH + lane + 64]);
            if (lane == 0) {
                out[row] = pp;
                out[BB * LL + row] = nn;
            }
        } else {
            seqs[row * HH + lane]      = y0;
            seqs[row * HH + lane + 64] = y1;
            if (do_qkv) {
                s_lds[wv][lane]      = y0;    // park y2 for QKV (own-row writes)
                s_lds[wv][lane + 64] = y1;
            }
        }
    }
    if (!do_qkv) return;
    __syncthreads();
    commit_w(pw, w_lds, t);                  // Wq into LDS
    __syncthreads();
    prefetch_w(Wk, pw, t);                   // hide Wk latency under Q GEMM
    // --- next-layer Q ---
    a0 = 0.f; a1 = 0.f;
#pragma unroll 4
    for (int k4 = 0; k4 < 32; ++k4) {
        float w0 = wrow[k4 * 4 + 0], w1 = wrow[k4 * 4 + 1];
        float w2 = wrow[k4 * 4 + 2], w3 = wrow[k4 * 4 + 3];
        float4 s0 = *(const float4*)&s_lds[rg * 2][k4 * 4];
        float4 s1 = *(const float4*)&s_lds[rg * 2 + 1][k4 * 4];
        a0 += s0.x * w0 + s0.y * w1 + s0.z * w2 + s0.w * w3;
        a1 += s1.x * w0 + s1.y * w1 + s1.z * w2 + s1.w * w3;
    }
    Q[(r0g + rg * 2) * HH + c]     = a0 + bq[c];
    Q[(r0g + rg * 2 + 1) * HH + c] = a1 + bq[c];
    __syncthreads();
    commit_w(pw, w_lds, t);
    __syncthreads();
    prefetch_w(Wv, pw, t);                   // hide Wv latency under K GEMM
    // --- next-layer K + posK ---
    a0 = 0.f; a1 = 0.f;
#pragma unroll 4
    for (int k4 = 0; k4 < 32; ++k4) {
        float w0 = wrow[k4 * 4 + 0], w1 = wrow[k4 * 4 + 1];
        float w2 = wrow[k4 * 4 + 2], w3 = wrow[k4 * 4 + 3];
        float4 s0 = *(const float4*)&s_lds[rg * 2][k4 * 4];
        float4 s1 = *(const float4*)&s_lds[rg * 2 + 1][k4 * 4];
        a0 += s0.x * w0 + s0.y * w1 + s0.z * w2 + s0.w * w3;
        a1 += s1.x * w0 + s1.y * w1 + s1.z * w2 + s1.w * w3;
    }
    {
        int row0 = r0g + rg * 2, row1 = row0 + 1;
        Kp[row0 * HH + c] = a0 + bk[c] + posK[(row0 % LL) * HH + c];
        Kp[row1 * HH + c] = a1 + bk[c] + posK[(row1 % LL) * HH + c];
    }
    __syncthreads();
    commit_w(pw, w_lds, t);
    __syncthreads();
    // --- next-layer V + posV ---
    a0 = 0.f; a1 = 0.f;
#pragma unroll 4
    for (int k4 = 0; k4 < 32; ++k4) {
        float w0 = wrow[k4 * 4 + 0], w1 = wrow[k4 * 4 + 1];
        float w2 = wrow[k4 * 4 + 2], w3 = wrow[k4 * 4 + 3];
        float4 s0 = *(const float4*)&s_lds[rg * 2][k4 * 4];
        float4 s1 = *(const float4*)&s_lds[rg * 2 + 1][k4 * 4];
        a0 += s0.x * w0 + s0.y * w1 + s0.z * w2 + s0.w * w3;
        a1 += s1.x * w0 + s1.y * w1 + s1.z * w2 + s1.w * w3;
    }
    {
        int row0 = r0g + rg * 2, row1 = row0 + 1;
        Vp[row0 * HH + c] = a0 + bv[c] + posV[(row0 % LL) * HH + c];
        Vp[row1 * HH + c] = a1 + bv[c] + posV[(row1 % LL) * HH + c];
    }
}

extern "C" void kernel_launch(void* const* d_in, const int* in_sizes, int n_in,
                              void* d_out, int out_size, void* d_ws, size_t ws_size,
                              hipStream_t stream) {
    const int* log_seqs = (const int*)d_in[1];
    const int* tm       = (const int*)d_in[2];
    const int* pos_seqs = (const int*)d_in[3];
    const int* neg_seqs = (const int*)d_in[4];
    const float* item_emb = (const float*)d_in[5];
    const float* posK   = (const float*)d_in[6];
    const float* posV   = (const float*)d_in[7];
    const float* timeK  = (const float*)d_in[8];
    const float* timeV  = (const float*)d_in[9];
    const float* Wq = (const float*)d_in[10];
    const float* bq = (const float*)d_in[11];
    const float* Wk = (const float*)d_in[12];
    const float* bk = (const float*)d_in[13];
    const float* Wv = (const float*)d_in[14];
    const float* bv = (const float*)d_in[15];
    const float* ln1_g = (const float*)d_in[16];
    const float* ln1_b = (const float*)d_in[17];
    const float* W1 = (const float*)d_in[18];
    const float* b1 = (const float*)d_in[19];
    const float* W2 = (const float*)d_in[20];
    const float* b2 = (const float*)d_in[21];
    const float* ln2_g = (const float*)d_in[22];
    const float* ln2_b = (const float*)d_in[23];
    const float* lnf_g = (const float*)d_in[24];
    const float* lnf_b = (const float*)d_in[25];

    float* ws    = (float*)d_ws;
    float* seqs  = ws;                   // 409600 floats each
    float* Qb    = seqs + 409600;
    float* Kpb   = Qb + 409600;
    float* Vpb   = Kpb + 409600;
    float* AO    = Vpb + 409600;
    float* projK = AO + 409600;          // 32*200*257 = 1,644,800

    // layer 0
    k_qkv<<<BB * LL / 16, 1024, 0, stream>>>(seqs, log_seqs, item_emb,
        Wq, bq, Wk, bk, Wv, bv, posK, posV, Qb, Kpb, Vpb);
    k_proj<<<32 * NQT, 256, 0, stream>>>(Qb, timeK, projK);
    k_attn<<<32 * NQT, 256, 0, stream>>>(Qb, Kpb, Vpb, projK, timeV,
                                         tm, log_seqs, AO);
    // layer-0 FFN fused with layer-1 QKV
    k_ffn_full<<<BB * LL / 16, 1024, 0, stream>>>(seqs, AO,
        ln1_g, ln1_b, W1, b1, W2, b2, ln2_g, ln2_b, log_seqs,
        1, Wq + HH * HH, bq + HH, Wk + HH * HH, bk + HH, Wv + HH * HH, bv + HH,
        posK, posV, Qb, Kpb, Vpb,
        0, lnf_g, lnf_b, item_emb, pos_seqs, neg_seqs, (float*)d_out);
    // layer 1
    k_proj<<<32 * NQT, 256, 0, stream>>>(Qb, timeK, projK);
    k_attn<<<32 * NQT, 256, 0, stream>>>(Qb, Kpb, Vpb, projK, timeV,
                                         tm, log_seqs, AO);
    k_ffn_full<<<BB * LL / 16, 1024, 0, stream>>>(seqs, AO,
        ln1_g + HH, ln1_b + HH, W1 + HH * HH, b1 + HH, W2 + HH * HH, b2 + HH,
        ln2_g + HH, ln2_b + HH, log_seqs,
        0, nullptr, nullptr, nullptr, nullptr, nullptr, nullptr,
        nullptr, nullptr, nullptr, nullptr, nullptr,
        1, lnf_g, lnf_b, item_emb, pos_seqs, neg_seqs, (float*)d_out);
}